// Round 8
// baseline (153.029 us; speedup 1.0000x reference)
//
#include <hip/hip_runtime.h>

#define RADIUS 5
#define WIN    11
#define WIN2   121
#define KCLS   6
#define HH     128
#define WW     128
#define BB     4
#define NPIX   (HH*WW)
#define TPB    256                  // 4 lanes per pixel, 64 px (half row)
#define NBLK   (BB*HH*2)            // 1024 blocks
#define PXB    64                   // pixels per block
#define LABW   (PXB + 2*RADIUS)     // 74 cols
#define NSITE  (WIN*LABW)           // 814 sites
#define PLSTR  (NSITE*2)            // floats per class-pair plane

__global__ __launch_bounds__(TPB, 4) void ncut_fused(
    const float* __restrict__ labels,
    const float* __restrict__ weights,
    float* __restrict__ acc,          // 48 floats: num[b][k] @ b*6+k, den @ 24+b*6+k
    unsigned* __restrict__ counter,
    float* __restrict__ out) {
  // label tile: 3 pair-planes of [site][2 classes] -> ds_read_b64 per pair
  __shared__ float shl[3 * PLSTR];    // 4884 floats = 19.5 KB
  __shared__ float shred[4 * 12];
  __shared__ int   lastFlag;

  const int tid = threadIdx.x;
  const int blk = blockIdx.x;
  const int b   = blk >> 8;                 // 256 blocks per image
  const int rem = blk & 255;
  const int y0  = rem >> 1;
  const int x0  = (rem & 1) * PXB;

  // ---- stage zero-padded label tile, class-pair interleaved ----
  const float* labB = labels + (size_t)b * KCLS * NPIX;
  for (int s = tid; s < NSITE; s += TPB) {
    const int tr = s / LABW;
    const int tc = s - tr * LABW;
    const int gy = y0 - RADIUS + tr;
    const int gx = x0 + tc - RADIUS;
    const bool ok = ((unsigned)gy < (unsigned)HH) & ((unsigned)gx < (unsigned)WW);
    const float* lp = labB + (size_t)gy * WW + gx;
#pragma unroll
    for (int p = 0; p < 3; ++p) {
      float2 v = make_float2(0.f, 0.f);
      if (ok) {
        v.x = lp[(size_t)(2 * p) * NPIX];
        v.y = lp[(size_t)(2 * p + 1) * NPIX];
      }
      *reinterpret_cast<float2*>(shl + p * PLSTR + 2 * s) = v;
    }
  }
  __syncthreads();

  // ---- per-thread: pixel px, tap o = 4j + q ----
  const int px = tid >> 2;          // 0..63
  const int q  = tid & 3;           // 0..3
  const float* wrowq = weights +
      ((size_t)b * NPIX + (size_t)y0 * WW + x0 + px) * WIN2 + q;

  float2 a0 = make_float2(0.f, 0.f);
  float2 a1 = make_float2(0.f, 0.f);
  float2 a2 = make_float2(0.f, 0.f);
  float wsum = 0.f;

#pragma unroll
  for (int j = 0; j < 30; ++j) {
    const int o4 = 4 * j;                 // group base tap (compile-time)
    const int S  = (o4 / WIN) * LABW + (o4 % WIN);
    const int Wn = WIN - (o4 % WIN);      // taps of this group in same row
    const float w = __builtin_nontemporal_load(wrowq + o4);  // tap o = 4j+q
    wsum += w;
    int li = px + S + q;
    if (Wn < 4) li += (q >= Wn) ? (LABW - WIN) : 0;  // row-wrap correction
    const float2 v0 = *reinterpret_cast<const float2*>(shl + 0 * PLSTR + 2 * li);
    const float2 v1 = *reinterpret_cast<const float2*>(shl + 1 * PLSTR + 2 * li);
    const float2 v2 = *reinterpret_cast<const float2*>(shl + 2 * PLSTR + 2 * li);
    a0.x += w * v0.x; a0.y += w * v0.y;
    a1.x += w * v1.x; a1.y += w * v1.y;
    a2.x += w * v2.x; a2.y += w * v2.y;
  }
  if (q == 0) {                      // tail tap o = 120
    const float w = __builtin_nontemporal_load(wrowq + 120);
    const int li = px + 10 * LABW + 10;
    wsum += w;
    const float2 v0 = *reinterpret_cast<const float2*>(shl + 0 * PLSTR + 2 * li);
    const float2 v1 = *reinterpret_cast<const float2*>(shl + 1 * PLSTR + 2 * li);
    const float2 v2 = *reinterpret_cast<const float2*>(shl + 2 * PLSTR + 2 * li);
    a0.x += w * v0.x; a0.y += w * v0.y;
    a1.x += w * v1.x; a1.y += w * v1.y;
    a2.x += w * v2.x; a2.y += w * v2.y;
  }

  // ---- reduce the 4 q-lanes (xor 1,2) ----
#pragma unroll
  for (int off = 1; off <= 2; off <<= 1) {
    wsum += __shfl_xor(wsum, off);
    a0.x += __shfl_xor(a0.x, off); a0.y += __shfl_xor(a0.y, off);
    a1.x += __shfl_xor(a1.x, off); a1.y += __shfl_xor(a1.y, off);
    a2.x += __shfl_xor(a2.x, off); a2.y += __shfl_xor(a2.y, off);
  }

  // ---- num/den per pixel (center site = 5*74 + 5) ----
  const int lc = px + 5 * LABW + 5;
  const float2 c0 = *reinterpret_cast<const float2*>(shl + 0 * PLSTR + 2 * lc);
  const float2 c1 = *reinterpret_cast<const float2*>(shl + 1 * PLSTR + 2 * lc);
  const float2 c2 = *reinterpret_cast<const float2*>(shl + 2 * PLSTR + 2 * lc);
  float nv[KCLS] = {c0.x * a0.x, c0.y * a0.y, c1.x * a1.x,
                    c1.y * a1.y, c2.x * a2.x, c2.y * a2.y};
  float dv[KCLS] = {c0.x * wsum, c0.y * wsum, c1.x * wsum,
                    c1.y * wsum, c2.x * wsum, c2.y * wsum};

  // ---- reduce across the 16 pixels of this wave (lane bits 2..5) ----
#pragma unroll
  for (int off = 4; off <= 32; off <<= 1) {
#pragma unroll
    for (int k = 0; k < KCLS; ++k) {
      nv[k] += __shfl_xor(nv[k], off);
      dv[k] += __shfl_xor(dv[k], off);
    }
  }
  const int wave = tid >> 6;
  if ((tid & 63) == 0) {
#pragma unroll
    for (int k = 0; k < KCLS; ++k) {
      shred[wave * 12 + k]     = nv[k];
      shred[wave * 12 + 6 + k] = dv[k];
    }
  }
  __syncthreads();

  // ---- block partial -> device accumulators (device-scope atomics) ----
  if (tid < 12) {
    float s = 0.f;
#pragma unroll
    for (int w = 0; w < 4; ++w) s += shred[w * 12 + tid];
    const int k     = tid % KCLS;
    const int isden = tid / KCLS;
    atomicAdd(acc + isden * 24 + b * KCLS + k, s);
  }
  __threadfence();                  // release: data-adds visible before counter
  __syncthreads();
  if (tid == 0) {
    unsigned old = atomicAdd(counter, 1u);
    lastFlag = (old == NBLK - 1) ? 1 : 0;
  }
  __syncthreads();
  if (!lastFlag) return;

  // ---- last block: final reduce of 48 accumulators ----
  float val = 0.f;
  if (tid < 24) {
    const float num = __hip_atomic_load(acc + tid,      __ATOMIC_ACQUIRE,
                                        __HIP_MEMORY_SCOPE_AGENT);
    const float den = __hip_atomic_load(acc + 24 + tid, __ATOMIC_ACQUIRE,
                                        __HIP_MEMORY_SCOPE_AGENT);
    val = fabsf(num / den) * (1.0f / BB);
  }
  if (tid < 64) {
#pragma unroll
    for (int off = 32; off; off >>= 1) val += __shfl_down(val, off);
    if (tid == 0) out[0] = (float)KCLS - val;
  }
}

extern "C" void kernel_launch(void* const* d_in, const int* in_sizes, int n_in,
                              void* d_out, int out_size, void* d_ws, size_t ws_size,
                              hipStream_t stream) {
  const float* labels  = (const float*)d_in[0];
  const float* weights = (const float*)d_in[1];
  float* out = (float*)d_out;
  float*    acc     = (float*)d_ws;                       // 48 floats
  unsigned* counter = (unsigned*)((char*)d_ws + 192);     // 1 uint

  hipMemsetAsync(d_ws, 0, 256, stream);                   // zero acc + counter
  ncut_fused<<<NBLK, TPB, 0, stream>>>(labels, weights, acc, counter, out);
}

// Round 9
// 79.375 us; speedup vs baseline: 1.9279x; 1.9279x over previous
//
#include <hip/hip_runtime.h>

#define RADIUS 5
#define WIN    11
#define WIN2   121
#define KCLS   6
#define HH     128
#define WW     128
#define BB     4
#define NPIX   (HH*WW)
#define TPB    256                  // 4 lanes per pixel, 64 px (half row)
#define NBLK   (BB*HH*2)            // 1024 blocks
#define PXB    64                   // pixels per block
#define LABW   (PXB + 2*RADIUS)     // 74 cols
#define NSITE  (WIN*LABW)           // 814 sites
#define PLSTR  (NSITE*2)            // floats per class-pair plane

__global__ __launch_bounds__(TPB, 4) void ncut_fused(
    const float* __restrict__ labels,
    const float* __restrict__ weights,
    float* __restrict__ acc,          // 48 floats: num[b][k] @ b*6+k, den @ 24+b*6+k
    unsigned* __restrict__ counter,
    float* __restrict__ out) {
  // label tile: 3 pair-planes of [site][2 classes] -> ds_read_b64 per pair
  __shared__ float shl[3 * PLSTR];    // 4884 floats = 19.5 KB
  __shared__ float shred[4 * 12];
  __shared__ int   lastFlag;

  const int tid = threadIdx.x;
  const int blk = blockIdx.x;
  const int b   = blk >> 8;                 // 256 blocks per image
  const int rem = blk & 255;
  const int y0  = rem >> 1;
  const int x0  = (rem & 1) * PXB;

  // ---- stage zero-padded label tile, class-pair interleaved ----
  const float* labB = labels + (size_t)b * KCLS * NPIX;
  for (int s = tid; s < NSITE; s += TPB) {
    const int tr = s / LABW;
    const int tc = s - tr * LABW;
    const int gy = y0 - RADIUS + tr;
    const int gx = x0 + tc - RADIUS;
    const bool ok = ((unsigned)gy < (unsigned)HH) & ((unsigned)gx < (unsigned)WW);
    const float* lp = labB + (size_t)gy * WW + gx;
#pragma unroll
    for (int p = 0; p < 3; ++p) {
      float2 v = make_float2(0.f, 0.f);
      if (ok) {
        v.x = lp[(size_t)(2 * p) * NPIX];
        v.y = lp[(size_t)(2 * p + 1) * NPIX];
      }
      *reinterpret_cast<float2*>(shl + p * PLSTR + 2 * s) = v;
    }
  }
  __syncthreads();

  // ---- per-thread: pixel px, tap o = 4j + q ----
  const int px = tid >> 2;          // 0..63
  const int q  = tid & 3;           // 0..3
  // per-instruction: 4 q-lanes read 4 CONSECUTIVE dwords (16B run per px)
  const float* wrowq = weights +
      ((size_t)b * NPIX + (size_t)y0 * WW + x0 + px) * WIN2 + q;

  float2 a0 = make_float2(0.f, 0.f);
  float2 a1 = make_float2(0.f, 0.f);
  float2 a2 = make_float2(0.f, 0.f);
  float wsum = 0.f;

#pragma unroll
  for (int j = 0; j < 30; ++j) {
    const int o4 = 4 * j;                 // group base tap (compile-time)
    const int S  = (o4 / WIN) * LABW + (o4 % WIN);
    const int Wn = WIN - (o4 % WIN);      // taps of this group in same row
    const float w = wrowq[o4];            // plain cached load (NT was 7x slower)
    wsum += w;
    int li = px + S + q;
    if (Wn < 4) li += (q >= Wn) ? (LABW - WIN) : 0;  // row-wrap correction
    const float2 v0 = *reinterpret_cast<const float2*>(shl + 0 * PLSTR + 2 * li);
    const float2 v1 = *reinterpret_cast<const float2*>(shl + 1 * PLSTR + 2 * li);
    const float2 v2 = *reinterpret_cast<const float2*>(shl + 2 * PLSTR + 2 * li);
    a0.x += w * v0.x; a0.y += w * v0.y;
    a1.x += w * v1.x; a1.y += w * v1.y;
    a2.x += w * v2.x; a2.y += w * v2.y;
  }
  if (q == 0) {                      // tail tap o = 120
    const float w = wrowq[120];
    const int li = px + 10 * LABW + 10;
    wsum += w;
    const float2 v0 = *reinterpret_cast<const float2*>(shl + 0 * PLSTR + 2 * li);
    const float2 v1 = *reinterpret_cast<const float2*>(shl + 1 * PLSTR + 2 * li);
    const float2 v2 = *reinterpret_cast<const float2*>(shl + 2 * PLSTR + 2 * li);
    a0.x += w * v0.x; a0.y += w * v0.y;
    a1.x += w * v1.x; a1.y += w * v1.y;
    a2.x += w * v2.x; a2.y += w * v2.y;
  }

  // ---- reduce the 4 q-lanes (xor 1,2) ----
#pragma unroll
  for (int off = 1; off <= 2; off <<= 1) {
    wsum += __shfl_xor(wsum, off);
    a0.x += __shfl_xor(a0.x, off); a0.y += __shfl_xor(a0.y, off);
    a1.x += __shfl_xor(a1.x, off); a1.y += __shfl_xor(a1.y, off);
    a2.x += __shfl_xor(a2.x, off); a2.y += __shfl_xor(a2.y, off);
  }

  // ---- num/den per pixel (center site = 5*74 + 5) ----
  const int lc = px + 5 * LABW + 5;
  const float2 c0 = *reinterpret_cast<const float2*>(shl + 0 * PLSTR + 2 * lc);
  const float2 c1 = *reinterpret_cast<const float2*>(shl + 1 * PLSTR + 2 * lc);
  const float2 c2 = *reinterpret_cast<const float2*>(shl + 2 * PLSTR + 2 * lc);
  float nv[KCLS] = {c0.x * a0.x, c0.y * a0.y, c1.x * a1.x,
                    c1.y * a1.y, c2.x * a2.x, c2.y * a2.y};
  float dv[KCLS] = {c0.x * wsum, c0.y * wsum, c1.x * wsum,
                    c1.y * wsum, c2.x * wsum, c2.y * wsum};

  // ---- reduce across the 16 pixels of this wave (lane bits 2..5) ----
#pragma unroll
  for (int off = 4; off <= 32; off <<= 1) {
#pragma unroll
    for (int k = 0; k < KCLS; ++k) {
      nv[k] += __shfl_xor(nv[k], off);
      dv[k] += __shfl_xor(dv[k], off);
    }
  }
  const int wave = tid >> 6;
  if ((tid & 63) == 0) {
#pragma unroll
    for (int k = 0; k < KCLS; ++k) {
      shred[wave * 12 + k]     = nv[k];
      shred[wave * 12 + 6 + k] = dv[k];
    }
  }
  __syncthreads();

  // ---- block partial -> device accumulators (device-scope atomics) ----
  if (tid < 12) {
    float s = 0.f;
#pragma unroll
    for (int w = 0; w < 4; ++w) s += shred[w * 12 + tid];
    const int k     = tid % KCLS;
    const int isden = tid / KCLS;
    atomicAdd(acc + isden * 24 + b * KCLS + k, s);
  }
  __threadfence();                  // release: data-adds visible before counter
  __syncthreads();
  if (tid == 0) {
    unsigned old = atomicAdd(counter, 1u);
    lastFlag = (old == NBLK - 1) ? 1 : 0;
  }
  __syncthreads();
  if (!lastFlag) return;

  // ---- last block: final reduce of 48 accumulators ----
  float val = 0.f;
  if (tid < 24) {
    const float num = __hip_atomic_load(acc + tid,      __ATOMIC_ACQUIRE,
                                        __HIP_MEMORY_SCOPE_AGENT);
    const float den = __hip_atomic_load(acc + 24 + tid, __ATOMIC_ACQUIRE,
                                        __HIP_MEMORY_SCOPE_AGENT);
    val = fabsf(num / den) * (1.0f / BB);
  }
  if (tid < 64) {
#pragma unroll
    for (int off = 32; off; off >>= 1) val += __shfl_down(val, off);
    if (tid == 0) out[0] = (float)KCLS - val;
  }
}

extern "C" void kernel_launch(void* const* d_in, const int* in_sizes, int n_in,
                              void* d_out, int out_size, void* d_ws, size_t ws_size,
                              hipStream_t stream) {
  const float* labels  = (const float*)d_in[0];
  const float* weights = (const float*)d_in[1];
  float* out = (float*)d_out;
  float*    acc     = (float*)d_ws;                       // 48 floats
  unsigned* counter = (unsigned*)((char*)d_ws + 192);     // 1 uint

  hipMemsetAsync(d_ws, 0, 256, stream);                   // zero acc + counter
  ncut_fused<<<NBLK, TPB, 0, stream>>>(labels, weights, acc, counter, out);
}

// Round 10
// 21.017 us; speedup vs baseline: 7.2813x; 3.7768x over previous
//
#include <hip/hip_runtime.h>

#define RADIUS 5
#define WIN    11
#define WIN2   121
#define KCLS   6
#define HH     128
#define WW     128
#define BB     4
#define NPIX   (HH*WW)
#define TPB    256                  // 4 lanes per pixel, 64 px (half row)
#define NBLK   (BB*HH*2)            // 1024 blocks
#define PXB    64                   // pixels per block
#define LABW   (PXB + 2*RADIUS)     // 74 cols
#define NSITE  (WIN*LABW)           // 814 sites
#define PLSTR  (NSITE*2)            // floats per class-pair plane

__global__ __launch_bounds__(TPB, 4) void ncut_main(
    const float* __restrict__ labels,
    const float* __restrict__ weights,
    float* __restrict__ part) {
  // label tile: 3 pair-planes of [site][2 classes] -> ds_read_b64 per pair
  __shared__ float shl[3 * PLSTR];    // 4884 floats = 19.5 KB
  __shared__ float shred[4 * 12];

  const int tid = threadIdx.x;
  const int blk = blockIdx.x;
  const int b   = blk >> 8;                 // 256 blocks per image
  const int rem = blk & 255;
  const int y0  = rem >> 1;
  const int x0  = (rem & 1) * PXB;

  // ---- stage zero-padded label tile, class-pair interleaved ----
  const float* labB = labels + (size_t)b * KCLS * NPIX;
  for (int s = tid; s < NSITE; s += TPB) {
    const int tr = s / LABW;
    const int tc = s - tr * LABW;
    const int gy = y0 - RADIUS + tr;
    const int gx = x0 + tc - RADIUS;
    const bool ok = ((unsigned)gy < (unsigned)HH) & ((unsigned)gx < (unsigned)WW);
    const float* lp = labB + (size_t)gy * WW + gx;
#pragma unroll
    for (int p = 0; p < 3; ++p) {
      float2 v = make_float2(0.f, 0.f);
      if (ok) {
        v.x = lp[(size_t)(2 * p) * NPIX];
        v.y = lp[(size_t)(2 * p + 1) * NPIX];
      }
      *reinterpret_cast<float2*>(shl + p * PLSTR + 2 * s) = v;
    }
  }

  // ---- per-thread: pixel px, tap o = 4j + q ----
  const int px = tid >> 2;          // 0..63
  const int q  = tid & 3;           // 0..3
  const float* wrowq = weights +
      ((size_t)b * NPIX + (size_t)y0 * WW + x0 + px) * WIN2 + q;

  // ---- PREFETCH BURST: all 31 weight taps into registers (one latency) ----
  float wv[31];
#pragma unroll
  for (int j = 0; j < 30; ++j) wv[j] = wrowq[4 * j];   // tap o = 4j + q
  wv[30] = wrowq[120 - q];          // q==0: tap 120; q>0: unused, in-bounds

  __syncthreads();                  // label tile ready (overlaps with loads)

  float2 a0 = make_float2(0.f, 0.f);
  float2 a1 = make_float2(0.f, 0.f);
  float2 a2 = make_float2(0.f, 0.f);
  float wsum = 0.f;

#pragma unroll
  for (int j = 0; j < 30; ++j) {
    const int o4 = 4 * j;                 // group base tap (compile-time)
    const int S  = (o4 / WIN) * LABW + (o4 % WIN);
    const int Wn = WIN - (o4 % WIN);      // taps of this group in same row
    const float w = wv[j];
    wsum += w;
    int li = px + S + q;
    if (Wn < 4) li += (q >= Wn) ? (LABW - WIN) : 0;  // row-wrap correction
    const float2 v0 = *reinterpret_cast<const float2*>(shl + 0 * PLSTR + 2 * li);
    const float2 v1 = *reinterpret_cast<const float2*>(shl + 1 * PLSTR + 2 * li);
    const float2 v2 = *reinterpret_cast<const float2*>(shl + 2 * PLSTR + 2 * li);
    a0.x += w * v0.x; a0.y += w * v0.y;
    a1.x += w * v1.x; a1.y += w * v1.y;
    a2.x += w * v2.x; a2.y += w * v2.y;
  }
  if (q == 0) {                      // tail tap o = 120
    const float w = wv[30];
    const int li = px + 10 * LABW + 10;
    wsum += w;
    const float2 v0 = *reinterpret_cast<const float2*>(shl + 0 * PLSTR + 2 * li);
    const float2 v1 = *reinterpret_cast<const float2*>(shl + 1 * PLSTR + 2 * li);
    const float2 v2 = *reinterpret_cast<const float2*>(shl + 2 * PLSTR + 2 * li);
    a0.x += w * v0.x; a0.y += w * v0.y;
    a1.x += w * v1.x; a1.y += w * v1.y;
    a2.x += w * v2.x; a2.y += w * v2.y;
  }

  // ---- reduce the 4 q-lanes (xor 1,2) ----
#pragma unroll
  for (int off = 1; off <= 2; off <<= 1) {
    wsum += __shfl_xor(wsum, off);
    a0.x += __shfl_xor(a0.x, off); a0.y += __shfl_xor(a0.y, off);
    a1.x += __shfl_xor(a1.x, off); a1.y += __shfl_xor(a1.y, off);
    a2.x += __shfl_xor(a2.x, off); a2.y += __shfl_xor(a2.y, off);
  }

  // ---- num/den per pixel (center site = 5*74 + 5) ----
  const int lc = px + 5 * LABW + 5;
  const float2 c0 = *reinterpret_cast<const float2*>(shl + 0 * PLSTR + 2 * lc);
  const float2 c1 = *reinterpret_cast<const float2*>(shl + 1 * PLSTR + 2 * lc);
  const float2 c2 = *reinterpret_cast<const float2*>(shl + 2 * PLSTR + 2 * lc);
  float nv[KCLS] = {c0.x * a0.x, c0.y * a0.y, c1.x * a1.x,
                    c1.y * a1.y, c2.x * a2.x, c2.y * a2.y};
  float dv[KCLS] = {c0.x * wsum, c0.y * wsum, c1.x * wsum,
                    c1.y * wsum, c2.x * wsum, c2.y * wsum};

  // ---- reduce across the 16 pixels of this wave (lane bits 2..5) ----
#pragma unroll
  for (int off = 4; off <= 32; off <<= 1) {
#pragma unroll
    for (int k = 0; k < KCLS; ++k) {
      nv[k] += __shfl_xor(nv[k], off);
      dv[k] += __shfl_xor(dv[k], off);
    }
  }
  const int wave = tid >> 6;
  if ((tid & 63) == 0) {
#pragma unroll
    for (int k = 0; k < KCLS; ++k) {
      shred[wave * 12 + k]     = nv[k];
      shred[wave * 12 + 6 + k] = dv[k];
    }
  }
  __syncthreads();
  if (tid < 12) {
    float s = 0.f;
#pragma unroll
    for (int w = 0; w < 4; ++w) s += shred[w * 12 + tid];
    part[blk * 12 + tid] = s;
  }
}

// ---- final: L = num/den per (b,k); out = K - (1/B) * sum |L| ----
// 8 segments x 32 (b,k)-slots, 32 block-partials each, LDS reduce.
__global__ __launch_bounds__(256) void ncut_final(
    const float* __restrict__ part, float* __restrict__ out) {
  __shared__ float shf[8 * 48];
  const int t   = threadIdx.x;
  const int seg = t >> 5;           // 0..7
  const int bk  = t & 31;           // active < 24
  if (bk < 24) {
    const int b = bk / KCLS;
    const int k = bk - b * KCLS;
    const int r0 = b * 256 + seg * 32;
    float num = 0.f, den = 0.f;
#pragma unroll 4
    for (int i = 0; i < 32; ++i) {
      const float* p = part + (size_t)(r0 + i) * 12;
      num += p[k];
      den += p[6 + k];
    }
    shf[seg * 48 + bk * 2]     = num;
    shf[seg * 48 + bk * 2 + 1] = den;
  }
  __syncthreads();
  float val = 0.f;
  if (t < 24) {
    float n = 0.f, d = 0.f;
#pragma unroll
    for (int s = 0; s < 8; ++s) {
      n += shf[s * 48 + t * 2];
      d += shf[s * 48 + t * 2 + 1];
    }
    val = fabsf(n / d) * (1.0f / BB);
  }
  if (t < 64) {
#pragma unroll
    for (int off = 16; off; off >>= 1) val += __shfl_down(val, off);
    if (t == 0) out[0] = (float)KCLS - val;
  }
}

extern "C" void kernel_launch(void* const* d_in, const int* in_sizes, int n_in,
                              void* d_out, int out_size, void* d_ws, size_t ws_size,
                              hipStream_t stream) {
  const float* labels  = (const float*)d_in[0];
  const float* weights = (const float*)d_in[1];
  float* out  = (float*)d_out;
  float* part = (float*)d_ws;      // 1024 blocks * 12 floats = 49152 B

  ncut_main<<<NBLK, TPB, 0, stream>>>(labels, weights, part);
  ncut_final<<<1, 256, 0, stream>>>(part, out);
}